// Round 1
// baseline (39.568 us; speedup 1.0000x reference)
//
#include <hip/hip_runtime.h>
#include <hip/hip_bf16.h>
#include <cstdint>

// Problem constants (from reference): B=16, T=1024, D=256, K=1024
#define M_ROWS 16384   // B*T
#define D_DIM  256
#define K_ROWS 1024

typedef __bf16 bf16x8 __attribute__((ext_vector_type(8)));
typedef __bf16 bf16x4 __attribute__((ext_vector_type(4)));
typedef float  f32x4  __attribute__((ext_vector_type(4)));

// async global->LDS, 16B per lane. LDS dest must be wave-uniform; HW writes
// lane l at (lds + l*16).
__device__ inline void load_lds16(const void* g, void* l) {
  __builtin_amdgcn_global_load_lds(
      (const __attribute__((address_space(1))) void*)(uintptr_t)g,
      (__attribute__((address_space(3))) void*)(uintptr_t)l,
      16, 0, 0);
}

// ---------------------------------------------------------------------------
// prep: f32 -> bf16 conversion + row squared-norms.
// One wave per row (rows 0..M-1 = x, rows M..M+K-1 = codebook).
// Lane l handles 4 consecutive floats (float4 load, 8B bf16 store).
// ---------------------------------------------------------------------------
__global__ __launch_bounds__(256) void prep_kernel(
    const float* __restrict__ x, const float* __restrict__ cb,
    __bf16* __restrict__ xbf, __bf16* __restrict__ cbf,
    float* __restrict__ xsq, float* __restrict__ csq)
{
  const int row = blockIdx.x * 4 + (threadIdx.x >> 6);
  const int l   = threadIdx.x & 63;

  const float* src;
  __bf16* dst;
  float* nrm;
  if (row < M_ROWS) {
    src = x   + (size_t)row * D_DIM;
    dst = xbf + (size_t)row * D_DIM;
    nrm = xsq + row;
  } else {
    const int r = row - M_ROWS;
    src = cb  + (size_t)r * D_DIM;
    dst = cbf + (size_t)r * D_DIM;
    nrm = csq + r;
  }

  const float4 v = reinterpret_cast<const float4*>(src)[l];
  float s = v.x * v.x + v.y * v.y + v.z * v.z + v.w * v.w;

  bf16x4 h;
  h[0] = (__bf16)v.x; h[1] = (__bf16)v.y; h[2] = (__bf16)v.z; h[3] = (__bf16)v.w;
  *reinterpret_cast<bf16x4*>(dst + l * 4) = h;

  #pragma unroll
  for (int o = 32; o > 0; o >>= 1) s += __shfl_xor(s, o);
  if (l == 0) *nrm = s;
}

// ---------------------------------------------------------------------------
// GEMM: out[m,k] = -p * (xsq[m] - 2*dot(x[m],c[k]) + csq[k])
// 128x128 tile, BK=32, 4 waves (2x2), 64x64 per wave, mfma_f32_16x16x32_bf16.
// Staging: global_load_lds width 16, linear LDS layout == row-major [128][32].
// ---------------------------------------------------------------------------
__global__ __launch_bounds__(256) void gemm_kernel(
    const __bf16* __restrict__ xbf, const __bf16* __restrict__ cbf,
    const float* __restrict__ xsq, const float* __restrict__ csq,
    const float* __restrict__ prec, float* __restrict__ out)
{
  __shared__ __bf16 At[128 * 32];
  __shared__ __bf16 Bt[128 * 32];

  const int tid = threadIdx.x;
  const int w   = tid >> 6;        // wave 0..3
  const int l   = tid & 63;
  const int wr  = w >> 1;          // wave row 0..1
  const int wc  = w & 1;           // wave col 0..1

  const int bx   = blockIdx.x;
  const int tc   = bx & 7;         // 8 column tiles (K=1024/128)
  const int tr   = bx >> 3;        // 128 row tiles
  const int row0 = tr * 128;
  const int col0 = tc * 128;

  // staging: thread t covers 16B at row (t>>2), col (t&3)*8 of the tile
  const int srow = tid >> 2;
  const int scol = (tid & 3) * 8;
  const __bf16* gA = xbf + (size_t)(row0 + srow) * D_DIM + scol;
  const __bf16* gB = cbf + (size_t)(col0 + srow) * D_DIM + scol;
  char* ldsA = (char*)At + w * 1024;   // wave-uniform base
  char* ldsB = (char*)Bt + w * 1024;

  f32x4 acc[4][4] = {};

  const int lr = l & 15;
  const int lk = (l >> 4) * 8;

  for (int k0 = 0; k0 < D_DIM; k0 += 32) {
    load_lds16(gA + k0,                       ldsA);
    load_lds16(gA + k0 + (size_t)64 * D_DIM,  ldsA + 4096);
    load_lds16(gB + k0,                       ldsB);
    load_lds16(gB + k0 + (size_t)64 * D_DIM,  ldsB + 4096);
    __syncthreads();

    bf16x8 af[4], bfm[4];
    #pragma unroll
    for (int f = 0; f < 4; ++f) {
      af[f]  = *reinterpret_cast<const bf16x8*>(&At[(wr * 64 + f * 16 + lr) * 32 + lk]);
      bfm[f] = *reinterpret_cast<const bf16x8*>(&Bt[(wc * 64 + f * 16 + lr) * 32 + lk]);
    }

    #pragma unroll
    for (int i = 0; i < 4; ++i)
      #pragma unroll
      for (int j = 0; j < 4; ++j)
        acc[i][j] = __builtin_amdgcn_mfma_f32_16x16x32_bf16(af[i], bfm[j], acc[i][j], 0, 0, 0);

    __syncthreads();
  }

  // epilogue: D mapping col = l&15, row = (l>>4)*4 + reg
  const float p  = prec[0];
  const int   lq = l >> 4;
  #pragma unroll
  for (int j = 0; j < 4; ++j) {
    const int colg = col0 + wc * 64 + j * 16 + lr;
    const float cs = csq[colg];
    #pragma unroll
    for (int i = 0; i < 4; ++i) {
      #pragma unroll
      for (int r = 0; r < 4; ++r) {
        const int rowg = row0 + wr * 64 + i * 16 + lq * 4 + r;
        const float xs = xsq[rowg];
        out[(size_t)rowg * K_ROWS + colg] = -p * (xs - 2.0f * acc[i][j][r] + cs);
      }
    }
  }
}

extern "C" void kernel_launch(void* const* d_in, const int* in_sizes, int n_in,
                              void* d_out, int out_size, void* d_ws, size_t ws_size,
                              hipStream_t stream) {
  const float* x    = (const float*)d_in[0];
  const float* cb   = (const float*)d_in[1];
  const float* prec = (const float*)d_in[2];
  float* out = (float*)d_out;

  char* ws = (char*)d_ws;
  __bf16* xbf = (__bf16*)ws;                    // 16384*256*2 = 8 MiB
  __bf16* cbf = (__bf16*)(ws + 8388608);        // 1024*256*2 = 512 KiB
  float*  xsq = (float*)(ws + 8912896);         // 16384*4 = 64 KiB
  float*  csq = (float*)(ws + 8978432);         // 1024*4 = 4 KiB

  // (M+K)/4 rows per block of 4 waves
  prep_kernel<<<(M_ROWS + K_ROWS) / 4, 256, 0, stream>>>(x, cb, xbf, cbf, xsq, csq);
  gemm_kernel<<<(M_ROWS / 128) * (K_ROWS / 128), 256, 0, stream>>>(xbf, cbf, xsq, csq, prec, out);
}

// Round 3
// 33.613 us; speedup vs baseline: 1.1772x; 1.1772x over previous
//
#include <hip/hip_runtime.h>
#include <hip/hip_bf16.h>
#include <cstdint>

// Problem constants: B=16, T=1024, D=256, K=1024
#define M_ROWS 16384   // B*T
#define D_DIM  256
#define K_ROWS 1024

typedef __bf16 bf16x8 __attribute__((ext_vector_type(8)));
typedef __bf16 bf16x4 __attribute__((ext_vector_type(4)));
typedef float  f32x4  __attribute__((ext_vector_type(4)));

// ---------------------------------------------------------------------------
// prep: f32 -> bf16 conversion + row squared-norms (f32-exact).
// One wave per row (rows 0..M-1 = x, rows M..M+K-1 = codebook).
// ---------------------------------------------------------------------------
__global__ __launch_bounds__(256) void prep_kernel(
    const float* __restrict__ x, const float* __restrict__ cb,
    __bf16* __restrict__ xbf, __bf16* __restrict__ cbf,
    float* __restrict__ xsq, float* __restrict__ csq)
{
  const int row = blockIdx.x * 4 + (threadIdx.x >> 6);
  const int l   = threadIdx.x & 63;

  const float* src;
  __bf16* dst;
  float* nrm;
  if (row < M_ROWS) {
    src = x   + (size_t)row * D_DIM;
    dst = xbf + (size_t)row * D_DIM;
    nrm = xsq + row;
  } else {
    const int r = row - M_ROWS;
    src = cb  + (size_t)r * D_DIM;
    dst = cbf + (size_t)r * D_DIM;
    nrm = csq + r;
  }

  const float4 v = reinterpret_cast<const float4*>(src)[l];
  float s = v.x * v.x + v.y * v.y + v.z * v.z + v.w * v.w;

  bf16x4 h;
  h[0] = (__bf16)v.x; h[1] = (__bf16)v.y; h[2] = (__bf16)v.z; h[3] = (__bf16)v.w;
  *reinterpret_cast<bf16x4*>(dst + l * 4) = h;

  #pragma unroll
  for (int o = 32; o > 0; o >>= 1) s += __shfl_xor(s, o);
  if (l == 0) *nrm = s;
}

// ---------------------------------------------------------------------------
// GEMM: out[m,k] = -p * (xsq[m] - 2*dot(x[m],c[k]) + csq[k])
// 128x128 tile, BK=64, 4 waves (2x2), 64x64 per wave, mfma_f32_16x16x32_bf16.
//
// Staging: REGISTER-staged (global bf16x8 -> ds_write_b128). LDS layout
// [128][64] bf16 with XOR swizzle applied on the WRITE address and the READ
// address (plain DS ops on both sides):
//     LDS[row][g] = G[row][g ^ (row&7)]        (g = 16B granule index 0..7)
// Write banks: granule (sg^(row&7)) -> each 4-bank group serves 8 distinct
// rows, balanced. Read banks: bank group = granule only; lanes 0..15 sweep
// all 8 granules (gk^(r&7)) -> 2 lanes/group = free.
//
// MFMA operands SWAPPED: mfma(cb_frag, x_frag) -> D reg axis = output COLUMN
// (codebook index), so the epilogue stores f32x4 of 4 consecutive columns.
// ---------------------------------------------------------------------------
__global__ __launch_bounds__(256) void gemm_kernel(
    const __bf16* __restrict__ xbf, const __bf16* __restrict__ cbf,
    const float* __restrict__ xsq, const float* __restrict__ csq,
    const float* __restrict__ prec, float* __restrict__ out)
{
  __shared__ __bf16 At[128 * 64];   // 16 KiB
  __shared__ __bf16 Bt[128 * 64];   // 16 KiB

  const int tid = threadIdx.x;
  const int w   = tid >> 6;        // wave 0..3
  const int l   = tid & 63;
  const int wr  = w >> 1;          // wave row 0..1
  const int wc  = w & 1;           // wave col 0..1

  // bijective XCD-chunked remap (1024 blocks % 8 == 0): XCD c owns tiles
  // [c*128,(c+1)*128) = a 16-wide tr band x all 8 tc -> 2MB x panel per XCD L2.
  const int bx   = blockIdx.x;
  const int tile = (bx & 7) * 128 + (bx >> 3);
  const int tr   = tile >> 3;      // 0..127
  const int tc   = tile & 7;       // 0..7
  const int row0 = tr * 128;
  const int col0 = tc * 128;

  // staging map: pass n (0..3), thread t -> row = n*32 + (t>>3), src granule t&7
  const int srow = tid >> 3;                 // 0..31
  const int sg   = tid & 7;                  // source 16B granule
  const int swg  = (sg ^ (srow & 7)) * 16;   // swizzled LDS granule byte
  const __bf16* gA = xbf + (size_t)(row0 + srow) * D_DIM + sg * 8;
  const __bf16* gB = cbf + (size_t)(col0 + srow) * D_DIM + sg * 8;
  char* const wA = (char*)At + srow * 128 + swg;
  char* const wB = (char*)Bt + srow * 128 + swg;

  f32x4 acc[4][4] = {};

  const int lr = l & 15;
  const int lk = l >> 4;           // 0..3

  // prologue: load k-step 0 into regs
  bf16x8 ra[4], rb[4];
  #pragma unroll
  for (int n = 0; n < 4; ++n) {
    ra[n] = *reinterpret_cast<const bf16x8*>(gA + (size_t)(n * 32) * D_DIM);
    rb[n] = *reinterpret_cast<const bf16x8*>(gB + (size_t)(n * 32) * D_DIM);
  }

  #pragma unroll
  for (int t = 0; t < 4; ++t) {
    // LDS is free to overwrite (first iter trivially; later: barrier at end
    // of previous MFMA phase).
    #pragma unroll
    for (int n = 0; n < 4; ++n) {
      *reinterpret_cast<bf16x8*>(wA + n * 4096) = ra[n];
      *reinterpret_cast<bf16x8*>(wB + n * 4096) = rb[n];
    }
    __syncthreads();

    // issue next k-step's global loads now: in flight during MFMA phase
    if (t < 3) {
      const int k0 = (t + 1) * 64;
      #pragma unroll
      for (int n = 0; n < 4; ++n) {
        ra[n] = *reinterpret_cast<const bf16x8*>(gA + (size_t)(n * 32) * D_DIM + k0);
        rb[n] = *reinterpret_cast<const bf16x8*>(gB + (size_t)(n * 32) * D_DIM + k0);
      }
    }

    #pragma unroll
    for (int ks = 0; ks < 2; ++ks) {
      bf16x8 af[4], bfm[4];
      #pragma unroll
      for (int f = 0; f < 4; ++f) {
        const int rar = wr * 64 + f * 16 + lr;
        af[f] = *reinterpret_cast<const bf16x8*>(
            (const char*)At + rar * 128 + ((ks * 64 + lk * 16) ^ ((rar & 7) << 4)));
        const int rbr = wc * 64 + f * 16 + lr;
        bfm[f] = *reinterpret_cast<const bf16x8*>(
            (const char*)Bt + rbr * 128 + ((ks * 64 + lk * 16) ^ ((rbr & 7) << 4)));
      }
      #pragma unroll
      for (int i = 0; i < 4; ++i)
        #pragma unroll
        for (int j = 0; j < 4; ++j)
          acc[i][j] = __builtin_amdgcn_mfma_f32_16x16x32_bf16(bfm[j], af[i], acc[i][j], 0, 0, 0);
    }
    __syncthreads();
  }

  // epilogue (swapped-operand D mapping):
  //   out-row = row0 + wr*64 + i*16 + (l&15)         (B-operand col = x row)
  //   out-col = col0 + wc*64 + j*16 + (l>>4)*4 + r   (A-operand row = cb idx)
  const float p = prec[0];
  #pragma unroll
  for (int i = 0; i < 4; ++i) {
    const int rowg = row0 + wr * 64 + i * 16 + lr;
    const float xs = xsq[rowg];
    float* orow = out + (size_t)rowg * K_ROWS;
    #pragma unroll
    for (int j = 0; j < 4; ++j) {
      const int colg = col0 + wc * 64 + j * 16 + lk * 4;
      const f32x4 cs = *reinterpret_cast<const f32x4*>(&csq[colg]);
      f32x4 v;
      #pragma unroll
      for (int r = 0; r < 4; ++r)
        v[r] = -p * (xs - 2.0f * acc[i][j][r] + cs[r]);
      *reinterpret_cast<f32x4*>(&orow[colg]) = v;
    }
  }
}

extern "C" void kernel_launch(void* const* d_in, const int* in_sizes, int n_in,
                              void* d_out, int out_size, void* d_ws, size_t ws_size,
                              hipStream_t stream) {
  const float* x    = (const float*)d_in[0];
  const float* cb   = (const float*)d_in[1];
  const float* prec = (const float*)d_in[2];
  float* out = (float*)d_out;

  char* ws = (char*)d_ws;
  __bf16* xbf = (__bf16*)ws;                    // 16384*256*2 = 8 MiB
  __bf16* cbf = (__bf16*)(ws + 8388608);        // 1024*256*2 = 512 KiB
  float*  xsq = (float*)(ws + 8912896);         // 16384*4 = 64 KiB
  float*  csq = (float*)(ws + 8978432);         // 1024*4 = 4 KiB

  prep_kernel<<<(M_ROWS + K_ROWS) / 4, 256, 0, stream>>>(x, cb, xbf, cbf, xsq, csq);
  gemm_kernel<<<(M_ROWS / 128) * (K_ROWS / 128), 256, 0, stream>>>(xbf, cbf, xsq, csq, prec, out);
}